// Round 1
// baseline (630.845 us; speedup 1.0000x reference)
//
#include <hip/hip_runtime.h>

// SelfAttention: B=8, S=2048, D=1024, U=1024, fp32 in/out.
// Pipeline (all-fp16 MFMA, fp32 accumulate):
//   prep:   W^T cast to fp16 (k-contiguous B operands), zero rowsum
//   qkv:    [16384,1024]x[1024,3072] -> Q,K fp16 [B,S,U]; V fp16 TRANSPOSED [B,U,S]
//   scores: per batch Q@K^T, epilogue exp(s/32) -> P fp16 [B,S,S] + rowsum atomics
//   pv:     per batch P@V (via Vt), epilogue * 1/rowsum -> fp32 out
// Workspace: 6.3 + 33.55*3 + 67.1 + 0.07 = 174.2 MB

#define BM 128
#define BN 128
#define BK 64
#define LDK 72   // padded LDS leading dim (halves): 144B row stride, 2-way max bank alias

typedef _Float16 half8  __attribute__((ext_vector_type(8)));
typedef _Float16 half4v __attribute__((ext_vector_type(4)));
typedef float    floatx4 __attribute__((ext_vector_type(4)));

// ---- common staging / compute helpers (256-thread blocks, 4 waves 2x2) ----

// stage a 128x64 fp16 tile (row-major, ld in elements) into LDS [128][LDK]
__device__ __forceinline__ void stage_half_tile(const _Float16* __restrict__ src, int ld,
                                                _Float16* __restrict__ dst, int t) {
#pragma unroll
    for (int i = 0; i < 4; ++i) {
        int idx = i * 256 + t;
        int row = idx >> 3, c8 = idx & 7;
        *(uint4*)(dst + row * LDK + c8 * 8) =
            *(const uint4*)(src + (size_t)row * ld + c8 * 8);
    }
}

// stage a 128x64 fp32 tile, casting to fp16, into LDS [128][LDK]
__device__ __forceinline__ void stage_float_tile(const float* __restrict__ src, int ld,
                                                 _Float16* __restrict__ dst, int t) {
#pragma unroll
    for (int i = 0; i < 8; ++i) {
        int idx = i * 256 + t;
        int row = idx >> 4, c4 = idx & 15;
        float4 v = *(const float4*)(src + (size_t)row * ld + c4 * 4);
        half4v h;
        h[0] = (_Float16)v.x; h[1] = (_Float16)v.y;
        h[2] = (_Float16)v.z; h[3] = (_Float16)v.w;
        *(half4v*)(dst + row * LDK + c4 * 4) = h;
    }
}

// one BK=64 K-step: 8 ds_read_b128 per kk-half + 16 MFMAs, 4x4 16x16 frags/wave
__device__ __forceinline__ void mfma_accum(const _Float16* __restrict__ As,
                                           const _Float16* __restrict__ Bs,
                                           int wm, int wn, int l15, int q4,
                                           floatx4 acc[4][4]) {
#pragma unroll
    for (int kk = 0; kk < BK; kk += 32) {
        half8 a[4], b[4];
#pragma unroll
        for (int i = 0; i < 4; ++i)
            a[i] = *(const half8*)(As + (wm * 64 + i * 16 + l15) * LDK + kk + q4 * 8);
#pragma unroll
        for (int j = 0; j < 4; ++j)
            b[j] = *(const half8*)(Bs + (wn * 64 + j * 16 + l15) * LDK + kk + q4 * 8);
#pragma unroll
        for (int i = 0; i < 4; ++i)
#pragma unroll
            for (int j = 0; j < 4; ++j)
                acc[i][j] = __builtin_amdgcn_mfma_f32_16x16x32_f16(a[i], b[j], acc[i][j], 0, 0, 0);
    }
}

// ---- kernel 1: transpose-cast weights to fp16, zero rowsum ----
// WbT[g][u][d] = W_g[d][u];  grid (32,32,3), block 256
__global__ void prep_weights(const float* __restrict__ Wq, const float* __restrict__ Wk,
                             const float* __restrict__ Wv, _Float16* __restrict__ WbT,
                             float* __restrict__ rowsum) {
    int g = blockIdx.z;
    const float* W = (g == 0) ? Wq : (g == 1) ? Wk : Wv;
    __shared__ float tile[32][33];
    int u0 = blockIdx.x * 32, d0 = blockIdx.y * 32;
    int tx = threadIdx.x & 31, ty = threadIdx.x >> 5;  // ty 0..7
#pragma unroll
    for (int i = 0; i < 32; i += 8)
        tile[ty + i][tx] = W[(size_t)(d0 + ty + i) * 1024 + (u0 + tx)];
    __syncthreads();
#pragma unroll
    for (int i = 0; i < 32; i += 8)
        WbT[(size_t)g * 1024 * 1024 + (size_t)(u0 + ty + i) * 1024 + (d0 + tx)] =
            (_Float16)tile[tx][ty + i];
    // zero rowsum (8*2048 floats) using the first blocks
    int gid = (blockIdx.z * gridDim.y + blockIdx.y) * gridDim.x + blockIdx.x;
    int tg = gid * 256 + threadIdx.x;
    if (tg < 8 * 2048) rowsum[tg] = 0.0f;
}

// ---- kernel 2: fused QKV projection ----
// C[16384,3072] = X[16384,1024] @ WbT^T ; n<1024->Q, <2048->K, else V (transposed store)
__global__ void qkv_gemm(const float* __restrict__ X, const _Float16* __restrict__ WbT,
                         _Float16* __restrict__ Qh, _Float16* __restrict__ Kh,
                         _Float16* __restrict__ Vt) {
    __shared__ __align__(16) _Float16 As[BM * LDK];
    __shared__ __align__(16) _Float16 Bs[BN * LDK];
    int t = threadIdx.x;
    int lane = t & 63, wave = t >> 6;
    int wm = wave >> 1, wn = wave & 1;
    int l15 = lane & 15, q4 = lane >> 4;
    int m0 = blockIdx.y * BM, n0 = blockIdx.x * BN;
    floatx4 acc[4][4] = {};
    for (int kt = 0; kt < 1024; kt += BK) {
        __syncthreads();
        stage_float_tile(X + (size_t)m0 * 1024 + kt, 1024, As, t);
        stage_half_tile(WbT + (size_t)n0 * 1024 + kt, 1024, Bs, t);
        __syncthreads();
        mfma_accum(As, Bs, wm, wn, l15, q4, acc);
    }
    // epilogue: C/D layout col=lane&15, row=(lane>>4)*4+reg
#pragma unroll
    for (int i = 0; i < 4; ++i)
#pragma unroll
        for (int j = 0; j < 4; ++j)
#pragma unroll
            for (int r = 0; r < 4; ++r) {
                int m = m0 + wm * 64 + i * 16 + q4 * 4 + r;
                int n = n0 + wn * 64 + j * 16 + l15;
                int which = n >> 10, u = n & 1023;
                int b = m >> 11, s = m & 2047;
                _Float16 val = (_Float16)acc[i][j][r];
                if (which == 0)      Qh[((size_t)b * 2048 + s) * 1024 + u] = val;
                else if (which == 1) Kh[((size_t)b * 2048 + s) * 1024 + u] = val;
                else                 Vt[((size_t)b * 1024 + u) * 2048 + s] = val;
            }
}

// ---- kernel 3: scores + exp + rowsum ----
// per batch: P = exp((Q @ K^T)/32) fp16 [2048,2048]; rowsum += row sums
__global__ void scores_gemm(const _Float16* __restrict__ Qh, const _Float16* __restrict__ Kh,
                            _Float16* __restrict__ P, float* __restrict__ rowsum) {
    __shared__ __align__(16) _Float16 As[BM * LDK];
    __shared__ __align__(16) _Float16 Bs[BN * LDK];
    int t = threadIdx.x;
    int lane = t & 63, wave = t >> 6;
    int wm = wave >> 1, wn = wave & 1;
    int l15 = lane & 15, q4 = lane >> 4;
    int m0 = blockIdx.y * BM, n0 = blockIdx.x * BN;
    int batch = blockIdx.z;
    const _Float16* A = Qh + (size_t)batch * 2048 * 1024;
    const _Float16* B = Kh + (size_t)batch * 2048 * 1024;
    floatx4 acc[4][4] = {};
    for (int kt = 0; kt < 1024; kt += BK) {
        __syncthreads();
        stage_half_tile(A + (size_t)m0 * 1024 + kt, 1024, As, t);
        stage_half_tile(B + (size_t)n0 * 1024 + kt, 1024, Bs, t);
        __syncthreads();
        mfma_accum(As, Bs, wm, wn, l15, q4, acc);
    }
    _Float16* Pb = P + (size_t)batch * 2048 * 2048;
    float* rs = rowsum + batch * 2048;
#pragma unroll
    for (int i = 0; i < 4; ++i)
#pragma unroll
        for (int r = 0; r < 4; ++r) {
            int m = m0 + wm * 64 + i * 16 + q4 * 4 + r;
            float sum = 0.0f;
#pragma unroll
            for (int j = 0; j < 4; ++j) {
                int n = n0 + wn * 64 + j * 16 + l15;
                float e = __expf(acc[i][j][r] * 0.03125f);  // 1/sqrt(1024)
                Pb[(size_t)m * 2048 + n] = (_Float16)e;
                sum += e;
            }
            sum += __shfl_xor(sum, 1);
            sum += __shfl_xor(sum, 2);
            sum += __shfl_xor(sum, 4);
            sum += __shfl_xor(sum, 8);
            if (l15 == 0) atomicAdd(&rs[m], sum);
        }
}

// ---- kernel 4: P @ V (via Vt) with 1/rowsum epilogue -> fp32 out ----
__global__ void pv_gemm(const _Float16* __restrict__ P, const _Float16* __restrict__ Vt,
                        const float* __restrict__ rowsum, float* __restrict__ out) {
    __shared__ __align__(16) _Float16 As[BM * LDK];
    __shared__ __align__(16) _Float16 Bs[BN * LDK];
    int t = threadIdx.x;
    int lane = t & 63, wave = t >> 6;
    int wm = wave >> 1, wn = wave & 1;
    int l15 = lane & 15, q4 = lane >> 4;
    int m0 = blockIdx.y * BM, n0 = blockIdx.x * BN;
    int batch = blockIdx.z;
    const _Float16* A = P + (size_t)batch * 2048 * 2048;
    const _Float16* B = Vt + (size_t)batch * 1024 * 2048;
    floatx4 acc[4][4] = {};
    for (int kt = 0; kt < 2048; kt += BK) {
        __syncthreads();
        stage_half_tile(A + (size_t)m0 * 2048 + kt, 2048, As, t);
        stage_half_tile(B + (size_t)n0 * 2048 + kt, 2048, Bs, t);
        __syncthreads();
        mfma_accum(As, Bs, wm, wn, l15, q4, acc);
    }
    const float* rs = rowsum + batch * 2048;
    float* ob = out + (size_t)batch * 2048 * 1024;
#pragma unroll
    for (int i = 0; i < 4; ++i)
#pragma unroll
        for (int r = 0; r < 4; ++r) {
            int m = m0 + wm * 64 + i * 16 + q4 * 4 + r;
            float inv = 1.0f / rs[m];
#pragma unroll
            for (int j = 0; j < 4; ++j) {
                int n = n0 + wn * 64 + j * 16 + l15;
                ob[(size_t)m * 1024 + n] = acc[i][j][r] * inv;
            }
        }
}

extern "C" void kernel_launch(void* const* d_in, const int* in_sizes, int n_in,
                              void* d_out, int out_size, void* d_ws, size_t ws_size,
                              hipStream_t stream) {
    const float* X  = (const float*)d_in[0];
    const float* Wq = (const float*)d_in[1];
    const float* Wk = (const float*)d_in[2];
    const float* Wv = (const float*)d_in[3];
    float* out = (float*)d_out;

    char* ws = (char*)d_ws;
    size_t off = 0;
    _Float16* WbT = (_Float16*)(ws + off); off += (size_t)3 * 1024 * 1024 * 2;   //  6.3 MB
    _Float16* Qh  = (_Float16*)(ws + off); off += (size_t)8 * 2048 * 1024 * 2;   // 33.6 MB
    _Float16* Kh  = (_Float16*)(ws + off); off += (size_t)8 * 2048 * 1024 * 2;   // 33.6 MB
    _Float16* Vt  = (_Float16*)(ws + off); off += (size_t)8 * 1024 * 2048 * 2;   // 33.6 MB
    _Float16* P   = (_Float16*)(ws + off); off += (size_t)8 * 2048 * 2048 * 2;   // 67.1 MB
    float* rowsum = (float*)(ws + off);    off += (size_t)8 * 2048 * 4;          // 64 KB

    prep_weights<<<dim3(32, 32, 3), 256, 0, stream>>>(Wq, Wk, Wv, WbT, rowsum);
    qkv_gemm   <<<dim3(24, 128, 1), 256, 0, stream>>>(X, WbT, Qh, Kh, Vt);
    scores_gemm<<<dim3(16, 16, 8),  256, 0, stream>>>(Qh, Kh, P, rowsum);
    pv_gemm    <<<dim3(8, 16, 8),   256, 0, stream>>>(P, Vt, rowsum, out);
}

// Round 2
// 428.948 us; speedup vs baseline: 1.4707x; 1.4707x over previous
//
#include <hip/hip_runtime.h>

// SelfAttention: B=8, S=2048, D=1024, U=1024, fp32 in/out.
// R2: m97-style GEMM cores — global_load_lds(16B) async staging + XOR-swizzled
// LDS layout (no pad; physical slot (row,c8) holds global colgroup c8^(row&7)).
// Pipeline:
//   cast_x:  X fp32 -> Xh fp16 [B*S, D]
//   prep:    W^T cast fp16 (k-contiguous), zero rowsum
//   qkv:     [16384,1024]x[1024,3072] -> Q,K fp16 [B,S,U]; V fp16 transposed [B,U,S]
//   scores:  per batch Q@K^T, epilogue exp(s/32) -> P fp16 + rowsum atomics
//   pv:      per batch P@Vt, epilogue * 1/rowsum -> fp32 out
// Workspace: 33.6(Xh) + 6.3(WbT) + 33.6*3(QKV) + 67.1(P) + 0.07 = 207.8 MB

#define BM 128
#define BN 128
#define BK 64

typedef _Float16 half8  __attribute__((ext_vector_type(8)));
typedef float    floatx4 __attribute__((ext_vector_type(4)));

// ---- async stage: 128x64 fp16 tile (row-major, ld elems) -> LDS, swizzled ----
// 256 threads = 4 waves; chunk (i*4+wave) covers linear lanes L=chunk*64+lane;
// physical LDS half-offset = L*8 (row=L>>3, c8=L&7); global colgroup = c8^(row&7).
__device__ __forceinline__ void stage_async(const _Float16* __restrict__ src, int ld,
                                            _Float16* __restrict__ dst, int wave, int lane) {
#pragma unroll
    for (int i = 0; i < 4; ++i) {
        int chunk = i * 4 + wave;
        int L = chunk * 64 + lane;
        int row = L >> 3, c8 = L & 7;
        int cg = c8 ^ (row & 7);
        __builtin_amdgcn_global_load_lds(
            (const __attribute__((address_space(1))) unsigned int*)(src + (size_t)row * ld + cg * 8),
            (__attribute__((address_space(3))) unsigned int*)(dst + chunk * 512),  // wave-uniform base
            16, 0, 0);
    }
}

// ---- one BK=64 K-step: swizzled ds_read_b128 frags + 16 MFMAs (4x4 16x16x32) ----
__device__ __forceinline__ void mfma_accum(const _Float16* __restrict__ As,
                                           const _Float16* __restrict__ Bs,
                                           int wm, int wn, int l15, int q4,
                                           floatx4 acc[4][4]) {
#pragma unroll
    for (int kk = 0; kk < 2; ++kk) {  // k halves: colgroups kk*4+q4
        half8 a[4], b[4];
#pragma unroll
        for (int i = 0; i < 4; ++i) {
            int row = wm * 64 + i * 16 + l15;
            int cg = (kk * 4 + q4) ^ (row & 7);
            a[i] = *(const half8*)(As + row * 64 + cg * 8);
        }
#pragma unroll
        for (int j = 0; j < 4; ++j) {
            int row = wn * 64 + j * 16 + l15;
            int cg = (kk * 4 + q4) ^ (row & 7);
            b[j] = *(const half8*)(Bs + row * 64 + cg * 8);
        }
#pragma unroll
        for (int i = 0; i < 4; ++i)
#pragma unroll
            for (int j = 0; j < 4; ++j)
                acc[i][j] = __builtin_amdgcn_mfma_f32_16x16x32_f16(a[i], b[j], acc[i][j], 0, 0, 0);
    }
}

// ---- kernel 0: cast X fp32 -> fp16 ----
__global__ void cast_x(const float* __restrict__ X, _Float16* __restrict__ Xh) {
    size_t i = ((size_t)blockIdx.x * 256 + threadIdx.x) * 8;
    float4 v0 = *(const float4*)(X + i);
    float4 v1 = *(const float4*)(X + i + 4);
    half8 h;
    h[0] = (_Float16)v0.x; h[1] = (_Float16)v0.y; h[2] = (_Float16)v0.z; h[3] = (_Float16)v0.w;
    h[4] = (_Float16)v1.x; h[5] = (_Float16)v1.y; h[6] = (_Float16)v1.z; h[7] = (_Float16)v1.w;
    *(half8*)(Xh + i) = h;
}

// ---- kernel 1: transpose-cast weights to fp16, zero rowsum ----
__global__ void prep_weights(const float* __restrict__ Wq, const float* __restrict__ Wk,
                             const float* __restrict__ Wv, _Float16* __restrict__ WbT,
                             float* __restrict__ rowsum) {
    int g = blockIdx.z;
    const float* W = (g == 0) ? Wq : (g == 1) ? Wk : Wv;
    __shared__ float tile[32][33];
    int u0 = blockIdx.x * 32, d0 = blockIdx.y * 32;
    int tx = threadIdx.x & 31, ty = threadIdx.x >> 5;
#pragma unroll
    for (int i = 0; i < 32; i += 8)
        tile[ty + i][tx] = W[(size_t)(d0 + ty + i) * 1024 + (u0 + tx)];
    __syncthreads();
#pragma unroll
    for (int i = 0; i < 32; i += 8)
        WbT[(size_t)g * 1024 * 1024 + (size_t)(u0 + ty + i) * 1024 + (d0 + tx)] =
            (_Float16)tile[tx][ty + i];
    int gid = (blockIdx.z * gridDim.y + blockIdx.y) * gridDim.x + blockIdx.x;
    int tg = gid * 256 + threadIdx.x;
    if (tg < 8 * 2048) rowsum[tg] = 0.0f;
}

// ---- kernel 2: fused QKV projection ----
__global__ void qkv_gemm(const _Float16* __restrict__ Xh, const _Float16* __restrict__ WbT,
                         _Float16* __restrict__ Qh, _Float16* __restrict__ Kh,
                         _Float16* __restrict__ Vt) {
    __shared__ __align__(16) _Float16 As[BM * BK];
    __shared__ __align__(16) _Float16 Bs[BN * BK];
    int t = threadIdx.x;
    int lane = t & 63, wave = t >> 6;
    int wm = wave >> 1, wn = wave & 1;
    int l15 = lane & 15, q4 = lane >> 4;
    int m0 = blockIdx.y * BM, n0 = blockIdx.x * BN;
    floatx4 acc[4][4] = {};
    for (int kt = 0; kt < 1024; kt += BK) {
        __syncthreads();
        stage_async(Xh + (size_t)m0 * 1024 + kt, 1024, As, wave, lane);
        stage_async(WbT + (size_t)n0 * 1024 + kt, 1024, Bs, wave, lane);
        __syncthreads();
        mfma_accum(As, Bs, wm, wn, l15, q4, acc);
    }
    // epilogue: C/D layout col=lane&15, row=(lane>>4)*4+reg
#pragma unroll
    for (int i = 0; i < 4; ++i)
#pragma unroll
        for (int j = 0; j < 4; ++j)
#pragma unroll
            for (int r = 0; r < 4; ++r) {
                int m = m0 + wm * 64 + i * 16 + q4 * 4 + r;
                int n = n0 + wn * 64 + j * 16 + l15;
                int which = n >> 10, u = n & 1023;
                int b = m >> 11, s = m & 2047;
                _Float16 val = (_Float16)acc[i][j][r];
                if (which == 0)      Qh[((size_t)b * 2048 + s) * 1024 + u] = val;
                else if (which == 1) Kh[((size_t)b * 2048 + s) * 1024 + u] = val;
                else                 Vt[((size_t)b * 1024 + u) * 2048 + s] = val;
            }
}

// ---- kernel 3: scores + exp + rowsum ----
__global__ void scores_gemm(const _Float16* __restrict__ Qh, const _Float16* __restrict__ Kh,
                            _Float16* __restrict__ P, float* __restrict__ rowsum) {
    __shared__ __align__(16) _Float16 As[BM * BK];
    __shared__ __align__(16) _Float16 Bs[BN * BK];
    int t = threadIdx.x;
    int lane = t & 63, wave = t >> 6;
    int wm = wave >> 1, wn = wave & 1;
    int l15 = lane & 15, q4 = lane >> 4;
    int m0 = blockIdx.y * BM, n0 = blockIdx.x * BN;
    int batch = blockIdx.z;
    const _Float16* A = Qh + (size_t)batch * 2048 * 1024;
    const _Float16* B = Kh + (size_t)batch * 2048 * 1024;
    floatx4 acc[4][4] = {};
    for (int kt = 0; kt < 1024; kt += BK) {
        __syncthreads();
        stage_async(A + (size_t)m0 * 1024 + kt, 1024, As, wave, lane);
        stage_async(B + (size_t)n0 * 1024 + kt, 1024, Bs, wave, lane);
        __syncthreads();
        mfma_accum(As, Bs, wm, wn, l15, q4, acc);
    }
    _Float16* Pb = P + (size_t)batch * 2048 * 2048;
    float* rs = rowsum + batch * 2048;
#pragma unroll
    for (int i = 0; i < 4; ++i)
#pragma unroll
        for (int r = 0; r < 4; ++r) {
            int m = m0 + wm * 64 + i * 16 + q4 * 4 + r;
            float sum = 0.0f;
#pragma unroll
            for (int j = 0; j < 4; ++j) {
                int n = n0 + wn * 64 + j * 16 + l15;
                float e = __expf(acc[i][j][r] * 0.03125f);  // 1/sqrt(1024)
                Pb[(size_t)m * 2048 + n] = (_Float16)e;
                sum += e;
            }
            sum += __shfl_xor(sum, 1);
            sum += __shfl_xor(sum, 2);
            sum += __shfl_xor(sum, 4);
            sum += __shfl_xor(sum, 8);
            if (l15 == 0) atomicAdd(&rs[m], sum);
        }
}

// ---- kernel 4: P @ V (via Vt) with 1/rowsum epilogue -> fp32 out ----
__global__ void pv_gemm(const _Float16* __restrict__ P, const _Float16* __restrict__ Vt,
                        const float* __restrict__ rowsum, float* __restrict__ out) {
    __shared__ __align__(16) _Float16 As[BM * BK];
    __shared__ __align__(16) _Float16 Bs[BN * BK];
    int t = threadIdx.x;
    int lane = t & 63, wave = t >> 6;
    int wm = wave >> 1, wn = wave & 1;
    int l15 = lane & 15, q4 = lane >> 4;
    int m0 = blockIdx.y * BM, n0 = blockIdx.x * BN;
    int batch = blockIdx.z;
    const _Float16* A = P + (size_t)batch * 2048 * 2048;
    const _Float16* B = Vt + (size_t)batch * 1024 * 2048;
    floatx4 acc[4][4] = {};
    for (int kt = 0; kt < 2048; kt += BK) {
        __syncthreads();
        stage_async(A + (size_t)m0 * 2048 + kt, 2048, As, wave, lane);
        stage_async(B + (size_t)n0 * 2048 + kt, 2048, Bs, wave, lane);
        __syncthreads();
        mfma_accum(As, Bs, wm, wn, l15, q4, acc);
    }
    const float* rs = rowsum + batch * 2048;
    float* ob = out + (size_t)batch * 2048 * 1024;
#pragma unroll
    for (int i = 0; i < 4; ++i)
#pragma unroll
        for (int r = 0; r < 4; ++r) {
            int m = m0 + wm * 64 + i * 16 + q4 * 4 + r;
            float inv = 1.0f / rs[m];
#pragma unroll
            for (int j = 0; j < 4; ++j) {
                int n = n0 + wn * 64 + j * 16 + l15;
                ob[(size_t)m * 1024 + n] = acc[i][j][r] * inv;
            }
        }
}

extern "C" void kernel_launch(void* const* d_in, const int* in_sizes, int n_in,
                              void* d_out, int out_size, void* d_ws, size_t ws_size,
                              hipStream_t stream) {
    const float* X  = (const float*)d_in[0];
    const float* Wq = (const float*)d_in[1];
    const float* Wk = (const float*)d_in[2];
    const float* Wv = (const float*)d_in[3];
    float* out = (float*)d_out;

    char* ws = (char*)d_ws;
    size_t off = 0;
    _Float16* Xh  = (_Float16*)(ws + off); off += (size_t)8 * 2048 * 1024 * 2;   // 33.6 MB
    _Float16* WbT = (_Float16*)(ws + off); off += (size_t)3 * 1024 * 1024 * 2;   //  6.3 MB
    _Float16* Qh  = (_Float16*)(ws + off); off += (size_t)8 * 2048 * 1024 * 2;   // 33.6 MB
    _Float16* Kh  = (_Float16*)(ws + off); off += (size_t)8 * 2048 * 1024 * 2;   // 33.6 MB
    _Float16* Vt  = (_Float16*)(ws + off); off += (size_t)8 * 1024 * 2048 * 2;   // 33.6 MB
    _Float16* P   = (_Float16*)(ws + off); off += (size_t)8 * 2048 * 2048 * 2;   // 67.1 MB
    float* rowsum = (float*)(ws + off);    off += (size_t)8 * 2048 * 4;          // 64 KB

    cast_x     <<<dim3(8192, 1, 1), 256, 0, stream>>>(X, Xh);
    prep_weights<<<dim3(32, 32, 3), 256, 0, stream>>>(Wq, Wk, Wv, WbT, rowsum);
    qkv_gemm   <<<dim3(24, 128, 1), 256, 0, stream>>>(Xh, WbT, Qh, Kh, Vt);
    scores_gemm<<<dim3(16, 16, 8),  256, 0, stream>>>(Qh, Kh, P, rowsum);
    pv_gemm    <<<dim3(8, 16, 8),   256, 0, stream>>>(P, Vt, rowsum, out);
}